// Round 1
// baseline (3117.822 us; speedup 1.0000x reference)
//
#include <hip/hip_runtime.h>

#define NN 50000
#define NE 800000
#define LSTRIDE 65   // 64+1: (65*l + k) % 32 == (l+k)%32 -> conflict-free per-lane rows

__device__ __forceinline__ float frelu(float x) { return fmaxf(x, 0.f); }

// acc[j] += sum_{k=0..63} lvec[k] * W[k*64 + j]
// lvec = per-lane LDS row (runtime-k indexable); W wave-uniform -> s_load weights,
// acc[64] fully static-indexed -> stays in VGPRs.
__device__ __forceinline__ void gemm_accum64(float* __restrict__ acc,
                                             const float* __restrict__ W,
                                             const float* lvec)
{
#pragma unroll 2
    for (int k = 0; k < 64; ++k) {
        const float xk = lvec[k];
        const float* __restrict__ wr = W + k * 64;
#pragma unroll
        for (int j = 0; j < 64; ++j) acc[j] = fmaf(xk, wr[j], acc[j]);
    }
}

// Pa = nf @ We1[0:64,:], Pb = nf @ We1[64:128,:]   (wave per node, lane = out feature)
__global__ __launch_bounds__(256) void pre_kernel(
    const float* __restrict__ nf, const float* __restrict__ We1,
    float* __restrict__ Pa, float* __restrict__ Pb)
{
    const int j = threadIdx.x & 63;
    const int node = (int)((blockIdx.x * blockDim.x + threadIdx.x) >> 6);
    if (node >= NN) return;
    const float* __restrict__ row = nf + (size_t)node * 64;  // wave-uniform -> s_load
    float a = 0.f, b = 0.f;
#pragma unroll 4
    for (int k = 0; k < 64; ++k) {
        const float x = row[k];
        a = fmaf(x, We1[k * 64 + j], a);
        b = fmaf(x, We1[(k + 64) * 64 + j], b);
    }
    Pa[(size_t)node * 64 + j] = a;
    Pb[(size_t)node * 64 + j] = b;
}

// One edge per lane; 64 edges per 1-wave block.
__global__ __launch_bounds__(64) void edge_kernel(
    const float* __restrict__ Pa, const float* __restrict__ Pb,
    const float* __restrict__ coord, const int* __restrict__ el,
    const float* __restrict__ We1, const float* __restrict__ be1,
    const float* __restrict__ We2, const float* __restrict__ be2,
    const float* __restrict__ Wc1, const float* __restrict__ bc1,
    const float* __restrict__ wc,
    float* __restrict__ agg_edge, float* __restrict__ agg3, float* __restrict__ cntv)
{
    __shared__ float lbuf[64 * LSTRIDE];
    const int lane = threadIdx.x;
    const int e = blockIdx.x * 64 + lane;   // NE == 12500*64, no tail
    float* lvec = &lbuf[lane * LSTRIDE];

    const int2 pr = ((const int2*)el)[e];
    const int nin = pr.x, nout = pr.y;

    const float cdx = coord[3 * nout + 0] - coord[3 * nin + 0];
    const float cdy = coord[3 * nout + 1] - coord[3 * nin + 1];
    const float cdz = coord[3 * nout + 2] - coord[3 * nin + 2];
    const float radial = cdx * cdx + cdy * cdy + cdz * cdz;

    // h = relu(Pa[nin] + Pb[nout] + radial*We1[128,:] + be1), staged to LDS per-lane
    {
        const float4* __restrict__ pa = (const float4*)(Pa + (size_t)nin * 64);
        const float4* __restrict__ pb = (const float4*)(Pb + (size_t)nout * 64);
        const float4* __restrict__ w1r = (const float4*)(We1 + 128 * 64);
        const float4* __restrict__ b1 = (const float4*)be1;
#pragma unroll
        for (int q = 0; q < 16; ++q) {
            const float4 a = pa[q], b = pb[q], w = w1r[q], bb = b1[q];
            lvec[4 * q + 0] = frelu(a.x + b.x + radial * w.x + bb.x);
            lvec[4 * q + 1] = frelu(a.y + b.y + radial * w.y + bb.y);
            lvec[4 * q + 2] = frelu(a.z + b.z + radial * w.z + bb.z);
            lvec[4 * q + 3] = frelu(a.w + b.w + radial * w.w + bb.w);
        }
    }

    // edge_feat = relu(h @ We2 + be2)
    float acc[64];
#pragma unroll
    for (int j = 0; j < 64; ++j) acc[j] = be2[j];
    gemm_accum64(acc, We2, lvec);

    float ef[64];
#pragma unroll
    for (int j = 0; j < 64; ++j) ef[j] = frelu(acc[j]);
    // overwrite h with ef for runtime-k access in GEMM3 (same wave -> ordered)
#pragma unroll
    for (int j = 0; j < 64; ++j) lvec[j] = ef[j];

    // trans_w = relu(edge_feat @ Wc1 + bc1) @ wc
#pragma unroll
    for (int j = 0; j < 64; ++j) acc[j] = bc1[j];
    gemm_accum64(acc, Wc1, lvec);

    float tw = 0.f;
#pragma unroll
    for (int j = 0; j < 64; ++j) tw = fmaf(frelu(acc[j]), wc[j], tw);

    // segment sums (node_out) via global fp32 atomics
    float* __restrict__ ae = agg_edge + (size_t)nout * 64;
#pragma unroll
    for (int j = 0; j < 64; ++j) atomicAdd(&ae[j], ef[j]);
    atomicAdd(&agg3[3 * nout + 0], cdx * tw);
    atomicAdd(&agg3[3 * nout + 1], cdy * tw);
    atomicAdd(&agg3[3 * nout + 2], cdz * tw);
    atomicAdd(&cntv[nout], 1.f);
}

// One node per lane. agg3_coordout: aggregated coord deltas on input, coord_out on exit.
__global__ __launch_bounds__(64) void node_kernel(
    const float* __restrict__ nf, const float* __restrict__ coord,
    const float* __restrict__ agg_edge, float* agg3_coordout,
    const float* __restrict__ cntv,
    const float* __restrict__ Wn1, const float* __restrict__ bn1,
    const float* __restrict__ Wn2, const float* __restrict__ bn2,
    float* __restrict__ out_feat)
{
    __shared__ float lbuf[64 * LSTRIDE];
    const int lane = threadIdx.x;
    const int n = blockIdx.x * 64 + lane;
    const bool active = (n < NN);
    const int nc = active ? n : (NN - 1);
    float* lvec = &lbuf[lane * LSTRIDE];

    if (active) {
        const float inv = 1.f / fmaxf(cntv[n], 1.f);
#pragma unroll
        for (int d = 0; d < 3; ++d) {
            const float a = agg3_coordout[3 * n + d];       // read accumulated delta
            agg3_coordout[3 * n + d] = coord[3 * n + d] + a * inv;  // write coord_out
        }
    }

    // stage nf row
    {
        const float4* __restrict__ fr = (const float4*)(nf + (size_t)nc * 64);
#pragma unroll
        for (int q = 0; q < 16; ++q) {
            const float4 v = fr[q];
            lvec[4 * q + 0] = v.x; lvec[4 * q + 1] = v.y;
            lvec[4 * q + 2] = v.z; lvec[4 * q + 3] = v.w;
        }
    }
    float acc[64];
#pragma unroll
    for (int j = 0; j < 64; ++j) acc[j] = bn1[j];
    gemm_accum64(acc, Wn1, lvec);

    // stage agg_edge row (overwrite, same wave)
    {
        const float4* __restrict__ ar = (const float4*)(agg_edge + (size_t)nc * 64);
#pragma unroll
        for (int q = 0; q < 16; ++q) {
            const float4 v = ar[q];
            lvec[4 * q + 0] = v.x; lvec[4 * q + 1] = v.y;
            lvec[4 * q + 2] = v.z; lvec[4 * q + 3] = v.w;
        }
    }
    gemm_accum64(acc, Wn1 + 64 * 64, lvec);

    // q = relu(.), staged for GEMM2
#pragma unroll
    for (int j = 0; j < 64; ++j) lvec[j] = frelu(acc[j]);
#pragma unroll
    for (int j = 0; j < 64; ++j) acc[j] = bn2[j];
    gemm_accum64(acc, Wn2, lvec);

    if (active) {
        float* __restrict__ orow = out_feat + (size_t)n * 64;
        const float* __restrict__ frow = nf + (size_t)n * 64;
#pragma unroll
        for (int q = 0; q < 16; ++q) {
            const float4 v = *(const float4*)(frow + 4 * q);
            float4 o;
            o.x = v.x + acc[4 * q + 0];
            o.y = v.y + acc[4 * q + 1];
            o.z = v.z + acc[4 * q + 2];
            o.w = v.w + acc[4 * q + 3];
            *(float4*)(orow + 4 * q) = o;
        }
    }
}

extern "C" void kernel_launch(void* const* d_in, const int* in_sizes, int n_in,
                              void* d_out, int out_size, void* d_ws, size_t ws_size,
                              hipStream_t stream)
{
    const float* nf    = (const float*)d_in[0];
    const float* coord = (const float*)d_in[1];
    const int*   el    = (const int*)d_in[2];
    const float* We1   = (const float*)d_in[3];
    const float* be1   = (const float*)d_in[4];
    const float* We2   = (const float*)d_in[5];
    const float* be2   = (const float*)d_in[6];
    const float* Wn1   = (const float*)d_in[7];
    const float* bn1   = (const float*)d_in[8];
    const float* Wn2   = (const float*)d_in[9];
    const float* bn2   = (const float*)d_in[10];
    const float* Wc1   = (const float*)d_in[11];
    const float* bc1   = (const float*)d_in[12];
    const float* wc    = (const float*)d_in[13];

    float* out_feat  = (float*)d_out;                       // N*64
    float* out_coord = out_feat + (size_t)NN * 64;          // N*3

    // Pa borrows the out_feat region (dead until node_kernel);
    // agg3 borrows the out_coord region (finalized in-place by node_kernel).
    float* Pa = out_feat;
    float* Pb = (float*)d_ws;                                // N*64
    float* agg_edge = Pb + (size_t)NN * 64;                  // N*64
    float* cntv = agg_edge + (size_t)NN * 64;                // N
    float* agg3 = out_coord;                                 // N*3
    // ws bytes needed: (64+64+1)*NN*4 = ~25.8 MB

    hipMemsetAsync(agg_edge, 0, (size_t)(NN * 64 + NN) * sizeof(float), stream);
    hipMemsetAsync(agg3, 0, (size_t)NN * 3 * sizeof(float), stream);

    pre_kernel<<<dim3((NN * 64) / 256), dim3(256), 0, stream>>>(nf, We1, Pa, Pb);

    edge_kernel<<<dim3(NE / 64), dim3(64), 0, stream>>>(
        Pa, Pb, coord, el, We1, be1, We2, be2, Wc1, bc1, wc,
        agg_edge, agg3, cntv);

    node_kernel<<<dim3((NN + 63) / 64), dim3(64), 0, stream>>>(
        nf, coord, agg_edge, agg3, cntv, Wn1, bn1, Wn2, bn2, out_feat);
}

// Round 2
// 488.543 us; speedup vs baseline: 6.3819x; 6.3819x over previous
//
#include <hip/hip_runtime.h>

#define NN 50000
#define NE 800000

typedef __bf16 bf16x8 __attribute__((ext_vector_type(8)));
typedef float  f32x4  __attribute__((ext_vector_type(4)));

__device__ __forceinline__ float frelu(float x) { return fmaxf(x, 0.f); }

// ---------------------------------------------------------------------------
// Pa = nf @ We1[0:64,:], Pb = nf @ We1[64:128,:]   (wave per node, lane = out feature)
__global__ __launch_bounds__(256) void pre_kernel(
    const float* __restrict__ nf, const float* __restrict__ We1,
    float* __restrict__ Pa, float* __restrict__ Pb)
{
    const int j = threadIdx.x & 63;
    const int node = (int)((blockIdx.x * blockDim.x + threadIdx.x) >> 6);
    if (node >= NN) return;
    const float* __restrict__ row = nf + (size_t)node * 64;  // wave-uniform -> s_load
    float a = 0.f, b = 0.f;
#pragma unroll 4
    for (int k = 0; k < 64; ++k) {
        const float x = row[k];
        a = fmaf(x, We1[k * 64 + j], a);
        b = fmaf(x, We1[(k + 64) * 64 + j], b);
    }
    Pa[(size_t)node * 64 + j] = a;
    Pb[(size_t)node * 64 + j] = b;
}

// ---------------------------------------------------------------------------
// Convert We2 / Wc1 to bf16, transposed to [n][k] so MFMA B-fragments are
// contiguous 16B loads: WT[n*64+k] = W[k*64+n].
__global__ __launch_bounds__(256) void wprep_kernel(
    const float* __restrict__ We2, const float* __restrict__ Wc1,
    __bf16* __restrict__ W2T, __bf16* __restrict__ Wc1T)
{
    const int idx = blockIdx.x * 256 + threadIdx.x;  // 0..4095
    const int n = idx & 63, k = idx >> 6;
    W2T[n * 64 + k]  = (__bf16)We2[k * 64 + n];
    Wc1T[n * 64 + k] = (__bf16)Wc1[k * 64 + n];
}

// ---------------------------------------------------------------------------
// Edge kernel: 4 independent waves / block, 64 edges / wave, MFMA GEMMs.
// A-frag (16x16x32): lane l holds row = l&15, k = (l>>4)*8 + i (i=0..7)
// B-frag:            lane l holds col = l&15, k = (l>>4)*8 + i
// C/D:               lane l, reg r: col = l&15, row = (l>>4)*4 + r
__global__ __launch_bounds__(256) void edge_mfma(
    const float* __restrict__ Pa, const float* __restrict__ Pb,
    const float* __restrict__ coord, const int* __restrict__ el,
    const float* __restrict__ We1, const float* __restrict__ be1,
    const __bf16* __restrict__ W2T, const float* __restrict__ be2,
    const __bf16* __restrict__ Wc1T, const float* __restrict__ bc1,
    const float* __restrict__ wc,
    float* __restrict__ agg_edge, float* __restrict__ agg3, float* __restrict__ cntv)
{
    __shared__ __align__(16) __bf16 tile[4][64 * 64];  // ef, XOR-swizzled
    __shared__ int   nin_s[4][64];
    __shared__ int   nout_s[4][64];
    __shared__ float rad_s[4][64];
    __shared__ float tw_s[4][64];

    const int w    = threadIdx.x >> 6;
    const int lane = threadIdx.x & 63;
    const int c    = lane & 15;   // column residue
    const int g    = lane >> 4;   // k-group / row-group
    const int ebase = blockIdx.x * 256 + w * 64;   // NE = 3125*256, no tail

    // ---- phase 1: lane = edge ----
    const int2 pr = ((const int2*)el)[ebase + lane];
    const int nin = pr.x, nout = pr.y;
    nin_s[w][lane]  = nin;
    nout_s[w][lane] = nout;
    const float cdx = coord[3 * nout + 0] - coord[3 * nin + 0];
    const float cdy = coord[3 * nout + 1] - coord[3 * nin + 1];
    const float cdz = coord[3 * nout + 2] - coord[3 * nin + 2];
    const float radial = cdx * cdx + cdy * cdy + cdz * cdz;
    rad_s[w][lane] = radial;

    // ---- build A fragments of h directly in MFMA A-layout ----
    bf16x8 af[4][2];
#pragma unroll
    for (int s = 0; s < 2; ++s) {
        const int k0 = s * 32 + g * 8;
        const float4 w1a = *(const float4*)(We1 + 128 * 64 + k0);
        const float4 w1b = *(const float4*)(We1 + 128 * 64 + k0 + 4);
        const float4 b1a = *(const float4*)(be1 + k0);
        const float4 b1b = *(const float4*)(be1 + k0 + 4);
#pragma unroll
        for (int m = 0; m < 4; ++m) {
            const int e  = m * 16 + c;
            const int ni = nin_s[w][e];
            const int no = nout_s[w][e];
            const float rad = rad_s[w][e];
            const float4 pa0 = *(const float4*)(Pa + (size_t)ni * 64 + k0);
            const float4 pa1 = *(const float4*)(Pa + (size_t)ni * 64 + k0 + 4);
            const float4 pb0 = *(const float4*)(Pb + (size_t)no * 64 + k0);
            const float4 pb1 = *(const float4*)(Pb + (size_t)no * 64 + k0 + 4);
            bf16x8 a;
            a[0] = (__bf16)frelu(pa0.x + pb0.x + rad * w1a.x + b1a.x);
            a[1] = (__bf16)frelu(pa0.y + pb0.y + rad * w1a.y + b1a.y);
            a[2] = (__bf16)frelu(pa0.z + pb0.z + rad * w1a.z + b1a.z);
            a[3] = (__bf16)frelu(pa0.w + pb0.w + rad * w1a.w + b1a.w);
            a[4] = (__bf16)frelu(pa1.x + pb1.x + rad * w1b.x + b1b.x);
            a[5] = (__bf16)frelu(pa1.y + pb1.y + rad * w1b.y + b1b.y);
            a[6] = (__bf16)frelu(pa1.z + pb1.z + rad * w1b.z + b1b.z);
            a[7] = (__bf16)frelu(pa1.w + pb1.w + rad * w1b.w + b1b.w);
            af[m][s] = a;
        }
    }

    // ---- GEMM1: ef = relu(h @ We2 + be2) ----
    bf16x8 b1f[4][2];
#pragma unroll
    for (int n = 0; n < 4; ++n)
#pragma unroll
        for (int s = 0; s < 2; ++s)
            b1f[n][s] = *(const bf16x8*)(W2T + (n * 16 + c) * 64 + s * 32 + g * 8);

    f32x4 c1[4][4];
#pragma unroll
    for (int n = 0; n < 4; ++n) {
        const float b = be2[n * 16 + c];
#pragma unroll
        for (int m = 0; m < 4; ++m) c1[m][n] = (f32x4){b, b, b, b};
    }
#pragma unroll
    for (int m = 0; m < 4; ++m)
#pragma unroll
        for (int n = 0; n < 4; ++n)
#pragma unroll
            for (int s = 0; s < 2; ++s)
                c1[m][n] = __builtin_amdgcn_mfma_f32_16x16x32_bf16(
                    af[m][s], b1f[n][s], c1[m][n], 0, 0, 0);

    // ---- relu, stash ef (bf16, swizzled LDS) + coalesced agg_edge atomics ----
#pragma unroll
    for (int m = 0; m < 4; ++m) {
        int noutv[4];
#pragma unroll
        for (int r = 0; r < 4; ++r) noutv[r] = nout_s[w][m * 16 + g * 4 + r];
#pragma unroll
        for (int n = 0; n < 4; ++n) {
#pragma unroll
            for (int r = 0; r < 4; ++r) {
                const float efv = frelu(c1[m][n][r]);
                const int e = m * 16 + g * 4 + r;
                tile[w][e * 64 + ((n * 16 + c) ^ ((e & 7) << 3))] = (__bf16)efv;
                atomicAdd(&agg_edge[(size_t)noutv[r] * 64 + n * 16 + c], efv);
            }
        }
    }

    // ---- GEMM2: t = relu(ef @ Wc1 + bc1) ----
    bf16x8 a2[4][2];
#pragma unroll
    for (int m = 0; m < 4; ++m) {
        const int e = m * 16 + c;
#pragma unroll
        for (int s = 0; s < 2; ++s) {
            const int k0 = s * 32 + g * 8;
            a2[m][s] = *(const bf16x8*)&tile[w][e * 64 + (k0 ^ ((e & 7) << 3))];
        }
    }
    bf16x8 b2f[4][2];
#pragma unroll
    for (int n = 0; n < 4; ++n)
#pragma unroll
        for (int s = 0; s < 2; ++s)
            b2f[n][s] = *(const bf16x8*)(Wc1T + (n * 16 + c) * 64 + s * 32 + g * 8);

    f32x4 c2[4][4];
#pragma unroll
    for (int n = 0; n < 4; ++n) {
        const float b = bc1[n * 16 + c];
#pragma unroll
        for (int m = 0; m < 4; ++m) c2[m][n] = (f32x4){b, b, b, b};
    }
#pragma unroll
    for (int m = 0; m < 4; ++m)
#pragma unroll
        for (int n = 0; n < 4; ++n)
#pragma unroll
            for (int s = 0; s < 2; ++s)
                c2[m][n] = __builtin_amdgcn_mfma_f32_16x16x32_bf16(
                    a2[m][s], b2f[n][s], c2[m][n], 0, 0, 0);

    // ---- tw = relu(c2) @ wc : 16-lane butterfly reduce ----
    float wcv[4];
#pragma unroll
    for (int n = 0; n < 4; ++n) wcv[n] = wc[n * 16 + c];
#pragma unroll
    for (int m = 0; m < 4; ++m) {
#pragma unroll
        for (int r = 0; r < 4; ++r) {
            float p = 0.f;
#pragma unroll
            for (int n = 0; n < 4; ++n) p = fmaf(frelu(c2[m][n][r]), wcv[n], p);
            p += __shfl_xor(p, 1);
            p += __shfl_xor(p, 2);
            p += __shfl_xor(p, 4);
            p += __shfl_xor(p, 8);
            if (c == 0) tw_s[w][m * 16 + g * 4 + r] = p;
        }
    }

    // ---- epilogue: lane = edge, coord atomics ----
    const float tw = tw_s[w][lane];
    atomicAdd(&agg3[3 * nout + 0], cdx * tw);
    atomicAdd(&agg3[3 * nout + 1], cdy * tw);
    atomicAdd(&agg3[3 * nout + 2], cdz * tw);
    atomicAdd(&cntv[nout], 1.f);
}

// ---------------------------------------------------------------------------
#define LSTRIDE 65
// acc[j] += sum_k lvec[k] * W[k*64+j]
__device__ __forceinline__ void gemm_accum64(float* __restrict__ acc,
                                             const float* __restrict__ W,
                                             const float* lvec)
{
#pragma unroll 2
    for (int k = 0; k < 64; ++k) {
        const float xk = lvec[k];
        const float* __restrict__ wr = W + k * 64;
#pragma unroll
        for (int j = 0; j < 64; ++j) acc[j] = fmaf(xk, wr[j], acc[j]);
    }
}

// One node per lane. agg3_coordout: aggregated deltas on input, coord_out on exit.
__global__ __launch_bounds__(64) void node_kernel(
    const float* __restrict__ nf, const float* __restrict__ coord,
    const float* __restrict__ agg_edge, float* agg3_coordout,
    const float* __restrict__ cntv,
    const float* __restrict__ Wn1, const float* __restrict__ bn1,
    const float* __restrict__ Wn2, const float* __restrict__ bn2,
    float* __restrict__ out_feat)
{
    __shared__ float lbuf[64 * LSTRIDE];
    const int lane = threadIdx.x;
    const int n = blockIdx.x * 64 + lane;
    const bool active = (n < NN);
    const int nc = active ? n : (NN - 1);
    float* lvec = &lbuf[lane * LSTRIDE];

    if (active) {
        const float inv = 1.f / fmaxf(cntv[n], 1.f);
#pragma unroll
        for (int d = 0; d < 3; ++d) {
            const float a = agg3_coordout[3 * n + d];
            agg3_coordout[3 * n + d] = coord[3 * n + d] + a * inv;
        }
    }

    {
        const float4* __restrict__ fr = (const float4*)(nf + (size_t)nc * 64);
#pragma unroll
        for (int q = 0; q < 16; ++q) {
            const float4 v = fr[q];
            lvec[4 * q + 0] = v.x; lvec[4 * q + 1] = v.y;
            lvec[4 * q + 2] = v.z; lvec[4 * q + 3] = v.w;
        }
    }
    float acc[64];
#pragma unroll
    for (int j = 0; j < 64; ++j) acc[j] = bn1[j];
    gemm_accum64(acc, Wn1, lvec);

    {
        const float4* __restrict__ ar = (const float4*)(agg_edge + (size_t)nc * 64);
#pragma unroll
        for (int q = 0; q < 16; ++q) {
            const float4 v = ar[q];
            lvec[4 * q + 0] = v.x; lvec[4 * q + 1] = v.y;
            lvec[4 * q + 2] = v.z; lvec[4 * q + 3] = v.w;
        }
    }
    gemm_accum64(acc, Wn1 + 64 * 64, lvec);

#pragma unroll
    for (int j = 0; j < 64; ++j) lvec[j] = frelu(acc[j]);
#pragma unroll
    for (int j = 0; j < 64; ++j) acc[j] = bn2[j];
    gemm_accum64(acc, Wn2, lvec);

    if (active) {
        float* __restrict__ orow = out_feat + (size_t)n * 64;
        const float* __restrict__ frow = nf + (size_t)n * 64;
#pragma unroll
        for (int q = 0; q < 16; ++q) {
            const float4 v = *(const float4*)(frow + 4 * q);
            float4 o;
            o.x = v.x + acc[4 * q + 0];
            o.y = v.y + acc[4 * q + 1];
            o.z = v.z + acc[4 * q + 2];
            o.w = v.w + acc[4 * q + 3];
            *(float4*)(orow + 4 * q) = o;
        }
    }
}

// ---------------------------------------------------------------------------
extern "C" void kernel_launch(void* const* d_in, const int* in_sizes, int n_in,
                              void* d_out, int out_size, void* d_ws, size_t ws_size,
                              hipStream_t stream)
{
    const float* nf    = (const float*)d_in[0];
    const float* coord = (const float*)d_in[1];
    const int*   el    = (const int*)d_in[2];
    const float* We1   = (const float*)d_in[3];
    const float* be1   = (const float*)d_in[4];
    const float* We2   = (const float*)d_in[5];
    const float* be2   = (const float*)d_in[6];
    const float* Wn1   = (const float*)d_in[7];
    const float* bn1   = (const float*)d_in[8];
    const float* Wn2   = (const float*)d_in[9];
    const float* bn2   = (const float*)d_in[10];
    const float* Wc1   = (const float*)d_in[11];
    const float* bc1   = (const float*)d_in[12];
    const float* wc    = (const float*)d_in[13];

    float* out_feat  = (float*)d_out;               // N*64
    float* out_coord = out_feat + (size_t)NN * 64;  // N*3

    float* Pa = out_feat;                 // borrow d_out until node_kernel
    float* Pb = (float*)d_ws;             // N*64
    float* agg_edge = Pb + (size_t)NN * 64;  // N*64
    float* cntv = agg_edge + (size_t)NN * 64; // N
    __bf16* W2T  = (__bf16*)(cntv + NN);  // 4096 bf16 (16B-aligned: offset 25.8e6 B)
    __bf16* Wc1T = W2T + 4096;            // 4096 bf16
    float* agg3 = out_coord;              // borrow out_coord, finalized in node_kernel

    hipMemsetAsync(agg_edge, 0, (size_t)(NN * 64 + NN) * sizeof(float), stream);
    hipMemsetAsync(agg3, 0, (size_t)NN * 3 * sizeof(float), stream);

    wprep_kernel<<<dim3(16), dim3(256), 0, stream>>>(We2, Wc1, W2T, Wc1T);
    pre_kernel<<<dim3((NN * 64) / 256), dim3(256), 0, stream>>>(nf, We1, Pa, Pb);

    edge_mfma<<<dim3(NE / 256), dim3(256), 0, stream>>>(
        Pa, Pb, coord, el, We1, be1, W2T, be2, Wc1T, bc1, wc,
        agg_edge, agg3, cntv);

    node_kernel<<<dim3((NN + 63) / 64), dim3(64), 0, stream>>>(
        nf, coord, agg_edge, agg3, cntv, Wn1, bn1, Wn2, bn2, out_feat);
}

// Round 3
// 323.077 us; speedup vs baseline: 9.6504x; 1.5122x over previous
//
#include <hip/hip_runtime.h>

#define NN 50000
#define NE 800000

typedef __bf16 bf16x8 __attribute__((ext_vector_type(8)));
typedef float  f32x4  __attribute__((ext_vector_type(4)));

__device__ __forceinline__ float frelu(float x) { return fmaxf(x, 0.f); }

// ===========================================================================
// Weight prep: bf16, transposed to [out_col][k] so MFMA B-frags are 16B loads.
__global__ __launch_bounds__(256) void wprep_kernel(
    const float* __restrict__ We1, const float* __restrict__ We2,
    const float* __restrict__ Wc1, const float* __restrict__ Wn1,
    const float* __restrict__ Wn2,
    __bf16* __restrict__ W1aT, __bf16* __restrict__ W1bT,
    __bf16* __restrict__ W2T,  __bf16* __restrict__ Wc1T,
    __bf16* __restrict__ Wn1T, __bf16* __restrict__ Wn2T)
{
    const int idx = blockIdx.x * 256 + threadIdx.x;   // 0..4095
    const int j = idx & 63, k = idx >> 6;
    W1aT[j * 64 + k] = (__bf16)We1[k * 64 + j];
    W1bT[j * 64 + k] = (__bf16)We1[(64 + k) * 64 + j];
    W2T [j * 64 + k] = (__bf16)We2[k * 64 + j];
    Wc1T[j * 64 + k] = (__bf16)Wc1[k * 64 + j];
    Wn2T[j * 64 + k] = (__bf16)Wn2[k * 64 + j];
    Wn1T[j * 128 + k]      = (__bf16)Wn1[k * 64 + j];
    Wn1T[j * 128 + 64 + k] = (__bf16)Wn1[(64 + k) * 64 + j];
}

// ===========================================================================
// Counting sort by node_out: histogram -> scan -> scatter.
__global__ __launch_bounds__(256) void hist_kernel(const int* __restrict__ el,
                                                   int* __restrict__ deg)
{
    const int e = blockIdx.x * 256 + threadIdx.x;     // NE = 3125*256 exact
    atomicAdd(&deg[el[2 * e + 1]], 1);
}

__global__ __launch_bounds__(1024) void scan_kernel(const int* __restrict__ deg,
                                                    int* __restrict__ base)
{
    __shared__ int ts[1024];
    const int t = threadIdx.x;
    const int CH = (NN + 1023) / 1024;                // 49
    const int lo = t * CH;
    const int hi = (lo + CH < NN) ? (lo + CH) : NN;
    int s = 0;
    for (int i = lo; i < hi; ++i) s += deg[i];
    ts[t] = s;
    __syncthreads();
    for (int d = 1; d < 1024; d <<= 1) {
        const int v = (t >= d) ? ts[t - d] : 0;
        __syncthreads();
        ts[t] += v;
        __syncthreads();
    }
    int run = ts[t] - s;                              // exclusive prefix
    for (int i = lo; i < hi; ++i) { base[i] = run; run += deg[i]; }
}

__global__ __launch_bounds__(256) void scatter_kernel(const int* __restrict__ el,
                                                      int* __restrict__ base,
                                                      int2* __restrict__ sorted_el)
{
    const int e = blockIdx.x * 256 + threadIdx.x;
    const int2 pr = ((const int2*)el)[e];
    const int pos = atomicAdd(&base[pr.y], 1);
    sorted_el[pos] = pr;
}

// ===========================================================================
// Pa = nf @ We1[0:64,:], Pb = nf @ We1[64:128,:] -> bf16. 4 waves/block, MFMA.
__global__ __launch_bounds__(256) void pre_mfma(
    const float* __restrict__ nf,
    const __bf16* __restrict__ W1aT, const __bf16* __restrict__ W1bT,
    __bf16* __restrict__ Pa, __bf16* __restrict__ Pb)
{
    const int w = threadIdx.x >> 6, lane = threadIdx.x & 63;
    const int c = lane & 15, g = lane >> 4;
    const int mbase = blockIdx.x * 256 + w * 64;

    bf16x8 af[4][2];
#pragma unroll
    for (int m = 0; m < 4; ++m) {
        int node = mbase + m * 16 + c;
        node = (node < NN) ? node : (NN - 1);
#pragma unroll
        for (int s = 0; s < 2; ++s) {
            const int k0 = s * 32 + g * 8;
            const float4 v0 = *(const float4*)(nf + (size_t)node * 64 + k0);
            const float4 v1 = *(const float4*)(nf + (size_t)node * 64 + k0 + 4);
            bf16x8 a;
            a[0] = (__bf16)v0.x; a[1] = (__bf16)v0.y; a[2] = (__bf16)v0.z; a[3] = (__bf16)v0.w;
            a[4] = (__bf16)v1.x; a[5] = (__bf16)v1.y; a[6] = (__bf16)v1.z; a[7] = (__bf16)v1.w;
            af[m][s] = a;
        }
    }

    // Pa
    {
        f32x4 cc[4][4];
#pragma unroll
        for (int m = 0; m < 4; ++m)
#pragma unroll
            for (int n = 0; n < 4; ++n) cc[m][n] = (f32x4){0.f, 0.f, 0.f, 0.f};
#pragma unroll
        for (int n = 0; n < 4; ++n)
#pragma unroll
            for (int s = 0; s < 2; ++s) {
                const bf16x8 b = *(const bf16x8*)(W1aT + (n * 16 + c) * 64 + s * 32 + g * 8);
#pragma unroll
                for (int m = 0; m < 4; ++m)
                    cc[m][n] = __builtin_amdgcn_mfma_f32_16x16x32_bf16(af[m][s], b, cc[m][n], 0, 0, 0);
            }
#pragma unroll
        for (int m = 0; m < 4; ++m)
#pragma unroll
            for (int n = 0; n < 4; ++n)
#pragma unroll
                for (int r = 0; r < 4; ++r) {
                    const int node = mbase + m * 16 + g * 4 + r;
                    if (node < NN) Pa[(size_t)node * 64 + n * 16 + c] = (__bf16)cc[m][n][r];
                }
    }
    // Pb
    {
        f32x4 cc[4][4];
#pragma unroll
        for (int m = 0; m < 4; ++m)
#pragma unroll
            for (int n = 0; n < 4; ++n) cc[m][n] = (f32x4){0.f, 0.f, 0.f, 0.f};
#pragma unroll
        for (int n = 0; n < 4; ++n)
#pragma unroll
            for (int s = 0; s < 2; ++s) {
                const bf16x8 b = *(const bf16x8*)(W1bT + (n * 16 + c) * 64 + s * 32 + g * 8);
#pragma unroll
                for (int m = 0; m < 4; ++m)
                    cc[m][n] = __builtin_amdgcn_mfma_f32_16x16x32_bf16(af[m][s], b, cc[m][n], 0, 0, 0);
            }
#pragma unroll
        for (int m = 0; m < 4; ++m)
#pragma unroll
            for (int n = 0; n < 4; ++n)
#pragma unroll
                for (int r = 0; r < 4; ++r) {
                    const int node = mbase + m * 16 + g * 4 + r;
                    if (node < NN) Pb[(size_t)node * 64 + n * 16 + c] = (__bf16)cc[m][n][r];
                }
    }
}

// ===========================================================================
// Edge kernel, sorted edges. 4 waves/block, 64 edges/wave, MFMA GEMMs,
// run-compressed segmented aggregation (edges sorted by nout).
__global__ __launch_bounds__(256) void edge_mfma(
    const __bf16* __restrict__ Pa, const __bf16* __restrict__ Pb,
    const float* __restrict__ coord, const int2* __restrict__ sorted_el,
    const float* __restrict__ We1, const float* __restrict__ be1,
    const __bf16* __restrict__ W2T, const float* __restrict__ be2,
    const __bf16* __restrict__ Wc1T, const float* __restrict__ bc1,
    const float* __restrict__ wc,
    float* __restrict__ agg_edge, float* __restrict__ agg3)
{
    __shared__ __align__(16) __bf16 tile[4][64 * 64];  // ef, XOR-swizzled
    __shared__ int   nin_s[4][64];
    __shared__ int   nout_s[4][64];
    __shared__ float rad_s[4][64];
    __shared__ float tw_s[4][64];
    __shared__ float cd_s[4][64][3];

    const int w    = threadIdx.x >> 6;
    const int lane = threadIdx.x & 63;
    const int c    = lane & 15;
    const int g    = lane >> 4;
    const int ebase = blockIdx.x * 256 + w * 64;       // NE = 3125*256 exact

    // ---- phase 1: lane = edge (sorted) ----
    const int2 pr = sorted_el[ebase + lane];
    const int nin = pr.x, nout = pr.y;
    nin_s[w][lane]  = nin;
    nout_s[w][lane] = nout;
    const float cdx = coord[3 * nout + 0] - coord[3 * nin + 0];
    const float cdy = coord[3 * nout + 1] - coord[3 * nin + 1];
    const float cdz = coord[3 * nout + 2] - coord[3 * nin + 2];
    rad_s[w][lane] = cdx * cdx + cdy * cdy + cdz * cdz;
    cd_s[w][lane][0] = cdx; cd_s[w][lane][1] = cdy; cd_s[w][lane][2] = cdz;

    // ---- build A fragments of h directly in MFMA A-layout ----
    bf16x8 af[4][2];
#pragma unroll
    for (int s = 0; s < 2; ++s) {
        const int k0 = s * 32 + g * 8;
        const float4 w1a = *(const float4*)(We1 + 128 * 64 + k0);
        const float4 w1b = *(const float4*)(We1 + 128 * 64 + k0 + 4);
        const float4 b1a = *(const float4*)(be1 + k0);
        const float4 b1b = *(const float4*)(be1 + k0 + 4);
        float wv[8] = {w1a.x, w1a.y, w1a.z, w1a.w, w1b.x, w1b.y, w1b.z, w1b.w};
        float bv[8] = {b1a.x, b1a.y, b1a.z, b1a.w, b1b.x, b1b.y, b1b.z, b1b.w};
#pragma unroll
        for (int m = 0; m < 4; ++m) {
            const int e  = m * 16 + c;
            const int ni = nin_s[w][e];
            const int no = nout_s[w][e];
            const float rad = rad_s[w][e];
            const bf16x8 pa = *(const bf16x8*)(Pa + (size_t)ni * 64 + k0);
            const bf16x8 pb = *(const bf16x8*)(Pb + (size_t)no * 64 + k0);
            bf16x8 a;
#pragma unroll
            for (int i = 0; i < 8; ++i)
                a[i] = (__bf16)frelu((float)pa[i] + (float)pb[i] + rad * wv[i] + bv[i]);
            af[m][s] = a;
        }
    }

    // ---- GEMM1: ef = relu(h @ We2 + be2) ----
    f32x4 c1[4][4];
#pragma unroll
    for (int n = 0; n < 4; ++n) {
        const float b = be2[n * 16 + c];
#pragma unroll
        for (int m = 0; m < 4; ++m) c1[m][n] = (f32x4){b, b, b, b};
    }
#pragma unroll
    for (int n = 0; n < 4; ++n)
#pragma unroll
        for (int s = 0; s < 2; ++s) {
            const bf16x8 b = *(const bf16x8*)(W2T + (n * 16 + c) * 64 + s * 32 + g * 8);
#pragma unroll
            for (int m = 0; m < 4; ++m)
                c1[m][n] = __builtin_amdgcn_mfma_f32_16x16x32_bf16(af[m][s], b, c1[m][n], 0, 0, 0);
        }

    // ---- relu -> stash ef (bf16, swizzled LDS) ----
#pragma unroll
    for (int m = 0; m < 4; ++m)
#pragma unroll
        for (int n = 0; n < 4; ++n)
#pragma unroll
            for (int r = 0; r < 4; ++r) {
                const int e = m * 16 + g * 4 + r;
                tile[w][e * 64 + ((n * 16 + c) ^ ((e & 7) << 3))] = (__bf16)frelu(c1[m][n][r]);
            }

    // ---- GEMM2: t = relu(ef @ Wc1 + bc1) ----
    bf16x8 a2[4][2];
#pragma unroll
    for (int m = 0; m < 4; ++m) {
        const int e = m * 16 + c;
#pragma unroll
        for (int s = 0; s < 2; ++s) {
            const int k0 = s * 32 + g * 8;
            a2[m][s] = *(const bf16x8*)&tile[w][e * 64 + (k0 ^ ((e & 7) << 3))];
        }
    }
    f32x4 c2[4][4];
#pragma unroll
    for (int n = 0; n < 4; ++n) {
        const float b = bc1[n * 16 + c];
#pragma unroll
        for (int m = 0; m < 4; ++m) c2[m][n] = (f32x4){b, b, b, b};
    }
#pragma unroll
    for (int n = 0; n < 4; ++n)
#pragma unroll
        for (int s = 0; s < 2; ++s) {
            const bf16x8 b = *(const bf16x8*)(Wc1T + (n * 16 + c) * 64 + s * 32 + g * 8);
#pragma unroll
            for (int m = 0; m < 4; ++m)
                c2[m][n] = __builtin_amdgcn_mfma_f32_16x16x32_bf16(a2[m][s], b, c2[m][n], 0, 0, 0);
        }

    // ---- tw = relu(c2) @ wc : 16-lane butterfly reduce ----
    float wcv[4];
#pragma unroll
    for (int n = 0; n < 4; ++n) wcv[n] = wc[n * 16 + c];
#pragma unroll
    for (int m = 0; m < 4; ++m) {
#pragma unroll
        for (int r = 0; r < 4; ++r) {
            float p = 0.f;
#pragma unroll
            for (int n = 0; n < 4; ++n) p = fmaf(frelu(c2[m][n][r]), wcv[n], p);
            p += __shfl_xor(p, 1);
            p += __shfl_xor(p, 2);
            p += __shfl_xor(p, 4);
            p += __shfl_xor(p, 8);
            if (c == 0) tw_s[w][m * 16 + g * 4 + r] = p;
        }
    }

    // ---- agg_edge: lane = feature column, run-compressed over sorted rows ----
    {
        int cur = nout_s[w][0];
        float acc = 0.f;
        for (int r = 0; r < 64; ++r) {
            acc += (float)tile[w][r * 64 + (lane ^ ((r & 7) << 3))];
            const int nxt = (r < 63) ? nout_s[w][r + 1] : -1;
            if (nxt != cur) {   // wave-uniform branch
                atomicAdd(&agg_edge[(size_t)cur * 64 + lane], acc);
                acc = 0.f;
                cur = nxt;
            }
        }
    }

    // ---- coord agg: 48 lanes = 16 row-chunks x 3 dims, run-compressed ----
    if (lane < 48) {
        const int dim = lane % 3, chunk = lane / 3;   // chunk 0..15
        const int r0 = chunk * 4;
        int cur = nout_s[w][r0];
        float acc = 0.f;
#pragma unroll
        for (int rr = 0; rr < 4; ++rr) {
            const int r = r0 + rr;
            acc += cd_s[w][r][dim] * tw_s[w][r];
            const int nxt = (rr < 3) ? nout_s[w][r + 1] : -1;
            if (nxt != cur) {
                atomicAdd(&agg3[3 * cur + dim], acc);
                acc = 0.f;
                cur = nxt;
            }
        }
    }
}

// ===========================================================================
// Node kernel: coord finalize + node MLP via MFMA. 4 waves/block.
__global__ __launch_bounds__(256) void node_mfma(
    const float* __restrict__ nf, const float* __restrict__ coord,
    const float* __restrict__ agg_edge, const int* __restrict__ deg,
    float* agg3_coordout,
    const __bf16* __restrict__ Wn1T, const float* __restrict__ bn1,
    const __bf16* __restrict__ Wn2T, const float* __restrict__ bn2,
    float* __restrict__ out_feat)
{
    __shared__ __align__(16) __bf16 tile[4][64 * 64];
    const int t = threadIdx.x;
    const int w = t >> 6, lane = t & 63, c = lane & 15, g = lane >> 4;
    const int nblk = blockIdx.x * 256;

    // coord_out = coord + agg3/max(cnt,1), in place (agg3 aliases out_coord)
    const int nodeT = nblk + t;
    if (nodeT < NN) {
        const float invc = 1.f / fmaxf((float)deg[nodeT], 1.f);
#pragma unroll
        for (int d = 0; d < 3; ++d) {
            const float a = agg3_coordout[3 * nodeT + d];
            agg3_coordout[3 * nodeT + d] = coord[3 * nodeT + d] + a * invc;
        }
    }

    const int mbase = nblk + w * 64;

    // A frags: [nf || agg_edge] rows, K=128 (s=0,1: nf; s=2,3: agg_edge)
    bf16x8 a1[4][4];
#pragma unroll
    for (int m = 0; m < 4; ++m) {
        int node = mbase + m * 16 + c;
        node = (node < NN) ? node : (NN - 1);
#pragma unroll
        for (int s = 0; s < 4; ++s) {
            const int k0 = s * 32 + g * 8;
            const float* src = (k0 < 64) ? (nf + (size_t)node * 64 + k0)
                                         : (agg_edge + (size_t)node * 64 + (k0 - 64));
            const float4 v0 = *(const float4*)src;
            const float4 v1 = *(const float4*)(src + 4);
            bf16x8 a;
            a[0] = (__bf16)v0.x; a[1] = (__bf16)v0.y; a[2] = (__bf16)v0.z; a[3] = (__bf16)v0.w;
            a[4] = (__bf16)v1.x; a[5] = (__bf16)v1.y; a[6] = (__bf16)v1.z; a[7] = (__bf16)v1.w;
            a1[m][s] = a;
        }
    }

    // GEMM1: h1 = relu([nf||agg] @ Wn1 + bn1)
    f32x4 c1[4][4];
#pragma unroll
    for (int n = 0; n < 4; ++n) {
        const float b = bn1[n * 16 + c];
#pragma unroll
        for (int m = 0; m < 4; ++m) c1[m][n] = (f32x4){b, b, b, b};
    }
#pragma unroll
    for (int n = 0; n < 4; ++n)
#pragma unroll
        for (int s = 0; s < 4; ++s) {
            const bf16x8 b = *(const bf16x8*)(Wn1T + (n * 16 + c) * 128 + s * 32 + g * 8);
#pragma unroll
            for (int m = 0; m < 4; ++m)
                c1[m][n] = __builtin_amdgcn_mfma_f32_16x16x32_bf16(a1[m][s], b, c1[m][n], 0, 0, 0);
        }

    // stash relu(h1) swizzled
#pragma unroll
    for (int m = 0; m < 4; ++m)
#pragma unroll
        for (int n = 0; n < 4; ++n)
#pragma unroll
            for (int r = 0; r < 4; ++r) {
                const int e = m * 16 + g * 4 + r;
                tile[w][e * 64 + ((n * 16 + c) ^ ((e & 7) << 3))] = (__bf16)frelu(c1[m][n][r]);
            }

    // GEMM2: nf_out = h1 @ Wn2 + bn2
    bf16x8 a2[4][2];
#pragma unroll
    for (int m = 0; m < 4; ++m) {
        const int e = m * 16 + c;
#pragma unroll
        for (int s = 0; s < 2; ++s) {
            const int k0 = s * 32 + g * 8;
            a2[m][s] = *(const bf16x8*)&tile[w][e * 64 + (k0 ^ ((e & 7) << 3))];
        }
    }
    f32x4 c2[4][4];
#pragma unroll
    for (int n = 0; n < 4; ++n) {
        const float b = bn2[n * 16 + c];
#pragma unroll
        for (int m = 0; m < 4; ++m) c2[m][n] = (f32x4){b, b, b, b};
    }
#pragma unroll
    for (int n = 0; n < 4; ++n)
#pragma unroll
        for (int s = 0; s < 2; ++s) {
            const bf16x8 b = *(const bf16x8*)(Wn2T + (n * 16 + c) * 64 + s * 32 + g * 8);
#pragma unroll
            for (int m = 0; m < 4; ++m)
                c2[m][n] = __builtin_amdgcn_mfma_f32_16x16x32_bf16(a2[m][s], b, c2[m][n], 0, 0, 0);
        }

    // store: out_feat = nf + c2
#pragma unroll
    for (int m = 0; m < 4; ++m)
#pragma unroll
        for (int n = 0; n < 4; ++n)
#pragma unroll
            for (int r = 0; r < 4; ++r) {
                const int node = mbase + m * 16 + g * 4 + r;
                if (node < NN) {
                    const int col = n * 16 + c;
                    out_feat[(size_t)node * 64 + col] =
                        nf[(size_t)node * 64 + col] + c2[m][n][r];
                }
            }
}

// ===========================================================================
extern "C" void kernel_launch(void* const* d_in, const int* in_sizes, int n_in,
                              void* d_out, int out_size, void* d_ws, size_t ws_size,
                              hipStream_t stream)
{
    const float* nf    = (const float*)d_in[0];
    const float* coord = (const float*)d_in[1];
    const int*   el    = (const int*)d_in[2];
    const float* We1   = (const float*)d_in[3];
    const float* be1   = (const float*)d_in[4];
    const float* We2   = (const float*)d_in[5];
    const float* be2   = (const float*)d_in[6];
    const float* Wn1   = (const float*)d_in[7];
    const float* bn1   = (const float*)d_in[8];
    const float* Wn2   = (const float*)d_in[9];
    const float* bn2   = (const float*)d_in[10];
    const float* Wc1   = (const float*)d_in[11];
    const float* bc1   = (const float*)d_in[12];
    const float* wc    = (const float*)d_in[13];

    float* out_feat  = (float*)d_out;               // N*64 f32
    float* out_coord = out_feat + (size_t)NN * 64;  // N*3 f32

    // d_out borrows: Pa (bf16, 6.4MB of out_feat's 12.8MB), agg3 (= out_coord)
    __bf16* Pa  = (__bf16*)d_out;
    float* agg3 = out_coord;

    // ws layout (bytes):
    char* ws = (char*)d_ws;
    __bf16* Pb       = (__bf16*)ws;                    //  6,400,000
    float* agg_edge  = (float*)(ws + 6400000);         // 12,800,000
    int*   deg       = (int*)(ws + 19200000);          //    200,000
    int*   base      = (int*)(ws + 19400000);          //    200,000
    int2*  sorted_el = (int2*)(ws + 19600000);         //  6,400,000
    __bf16* W1aT = (__bf16*)(ws + 26000000);           // 8192 B each
    __bf16* W1bT = W1aT + 4096;
    __bf16* W2T  = W1bT + 4096;
    __bf16* Wc1T = W2T + 4096;
    __bf16* Wn2T = Wc1T + 4096;
    __bf16* Wn1T = Wn2T + 4096;                        // 16384 B
    // total ws usage ~26.06 MB

    hipMemsetAsync(deg, 0, (size_t)NN * sizeof(int), stream);
    hipMemsetAsync(agg_edge, 0, (size_t)NN * 64 * sizeof(float), stream);
    hipMemsetAsync(agg3, 0, (size_t)NN * 3 * sizeof(float), stream);

    wprep_kernel<<<dim3(16), dim3(256), 0, stream>>>(
        We1, We2, Wc1, Wn1, Wn2, W1aT, W1bT, W2T, Wc1T, Wn1T, Wn2T);

    hist_kernel<<<dim3(NE / 256), dim3(256), 0, stream>>>(el, deg);
    scan_kernel<<<dim3(1), dim3(1024), 0, stream>>>(deg, base);
    scatter_kernel<<<dim3(NE / 256), dim3(256), 0, stream>>>(el, base, sorted_el);

    pre_mfma<<<dim3((NN + 255) / 256), dim3(256), 0, stream>>>(nf, W1aT, W1bT, Pa, Pb);

    edge_mfma<<<dim3(NE / 256), dim3(256), 0, stream>>>(
        Pa, Pb, coord, sorted_el, We1, be1, W2T, be2, Wc1T, bc1, wc,
        agg_edge, agg3);

    node_mfma<<<dim3((NN + 255) / 256), dim3(256), 0, stream>>>(
        nf, coord, agg_edge, deg, agg3, Wn1T, bn1, Wn2T, bn2, out_feat);
}

// Round 5
// 282.295 us; speedup vs baseline: 11.0445x; 1.1445x over previous
//
#include <hip/hip_runtime.h>

#define NN 50000
#define NE 800000
#define PREP_BLOCKS 200
#define PREP_THREADS (PREP_BLOCKS * 256)

typedef __bf16 bf16x8 __attribute__((ext_vector_type(8)));
typedef float  f32x4  __attribute__((ext_vector_type(4)));

__device__ __forceinline__ float frelu(float x) { return fmaxf(x, 0.f); }

// ===========================================================================
// prep: transposed-weight prep (for LATER kernels) + agg_edge zero +
//       edge histogram with ranks + Pa/Pb node precompute (MFMA, We1 via
//       block-local LDS transpose -- no cross-block dependency).
__global__ __launch_bounds__(256) void prep_kernel(
    const float* __restrict__ nf, const int* __restrict__ el,
    const float* __restrict__ We1, const float* __restrict__ We2,
    const float* __restrict__ Wc1, const float* __restrict__ Wn1,
    const float* __restrict__ Wn2, const float* __restrict__ be1,
    __bf16* __restrict__ W2T,  __bf16* __restrict__ Wc1T,
    __bf16* __restrict__ Wn1T, __bf16* __restrict__ Wn2T,
    __bf16* __restrict__ Pa, __bf16* __restrict__ Pb,
    int* __restrict__ deg, int* __restrict__ rank, float* __restrict__ agg_edge)
{
    // Block-local transpose of We1[0:128,:] -> LDS, XOR-swizzled:
    // w1lds[j*128 + (k ^ ((j&7)<<3))] = We1[k*64+j]   (j=out col, k=0..127)
    __shared__ __align__(16) __bf16 w1lds[64 * 128];
    for (int idx = threadIdx.x; idx < 64 * 128; idx += 256) {
        const int k = idx >> 6;          // 0..127
        const int j = idx & 63;
        w1lds[j * 128 + (k ^ ((j & 7) << 3))] = (__bf16)We1[k * 64 + j];
    }

    const int tid = blockIdx.x * 256 + threadIdx.x;

    // ---- weight transpose for later kernels (first 4096 threads) ----
    if (tid < 4096) {
        const int j = tid & 63, k = tid >> 6;
        W2T [j * 64 + k] = (__bf16)We2[k * 64 + j];
        Wc1T[j * 64 + k] = (__bf16)Wc1[k * 64 + j];
        Wn2T[j * 64 + k] = (__bf16)Wn2[k * 64 + j];
        Wn1T[j * 128 + k]      = (__bf16)Wn1[k * 64 + j];
        Wn1T[j * 128 + 64 + k] = (__bf16)Wn1[(64 + k) * 64 + j];
    }

    // ---- agg_edge zero (3.2M floats as float4) ----
    {
        const f32x4 z = (f32x4){0.f, 0.f, 0.f, 0.f};
        for (int i = tid; i < NN * 16; i += PREP_THREADS)
            ((f32x4*)agg_edge)[i] = z;
    }

    // ---- histogram + rank (deg memset to 0 before this kernel) ----
    for (int e = tid; e < NE; e += PREP_THREADS) {
        const int2 pr = ((const int2*)el)[e];
        rank[e] = atomicAdd(&deg[pr.y], 1);
    }

    __syncthreads();   // w1lds ready

    // ---- Pa/Pb MFMA precompute (blocks 0..195) ----
    if (blockIdx.x >= 196) return;
    const int w = threadIdx.x >> 6, lane = threadIdx.x & 63;
    const int c = lane & 15, g = lane >> 4;
    const int mbase = blockIdx.x * 256 + w * 64;

    bf16x8 af[4][2];
#pragma unroll
    for (int m = 0; m < 4; ++m) {
        int node = mbase + m * 16 + c;
        node = (node < NN) ? node : (NN - 1);
#pragma unroll
        for (int s = 0; s < 2; ++s) {
            const int k0 = s * 32 + g * 8;
            const float4 v0 = *(const float4*)(nf + (size_t)node * 64 + k0);
            const float4 v1 = *(const float4*)(nf + (size_t)node * 64 + k0 + 4);
            bf16x8 a;
            a[0] = (__bf16)v0.x; a[1] = (__bf16)v0.y; a[2] = (__bf16)v0.z; a[3] = (__bf16)v0.w;
            a[4] = (__bf16)v1.x; a[5] = (__bf16)v1.y; a[6] = (__bf16)v1.z; a[7] = (__bf16)v1.w;
            af[m][s] = a;
        }
    }

    // Pa = nf @ We1[0:64,:]
    {
        f32x4 cc[4][4];
#pragma unroll
        for (int m = 0; m < 4; ++m)
#pragma unroll
            for (int n = 0; n < 4; ++n) cc[m][n] = (f32x4){0.f, 0.f, 0.f, 0.f};
#pragma unroll
        for (int n = 0; n < 4; ++n)
#pragma unroll
            for (int s = 0; s < 2; ++s) {
                const int j = n * 16 + c;
                const bf16x8 b = *(const bf16x8*)&w1lds[j * 128 + ((s * 32 + g * 8) ^ ((j & 7) << 3))];
#pragma unroll
                for (int m = 0; m < 4; ++m)
                    cc[m][n] = __builtin_amdgcn_mfma_f32_16x16x32_bf16(af[m][s], b, cc[m][n], 0, 0, 0);
            }
#pragma unroll
        for (int m = 0; m < 4; ++m)
#pragma unroll
            for (int n = 0; n < 4; ++n)
#pragma unroll
                for (int r = 0; r < 4; ++r) {
                    const int node = mbase + m * 16 + g * 4 + r;
                    if (node < NN) Pa[(size_t)node * 64 + n * 16 + c] = (__bf16)cc[m][n][r];
                }
    }
    // Pb = nf @ We1[64:128,:] + be1 (folded)
    {
        f32x4 cc[4][4];
#pragma unroll
        for (int m = 0; m < 4; ++m)
#pragma unroll
            for (int n = 0; n < 4; ++n) cc[m][n] = (f32x4){0.f, 0.f, 0.f, 0.f};
#pragma unroll
        for (int n = 0; n < 4; ++n)
#pragma unroll
            for (int s = 0; s < 2; ++s) {
                const int j = n * 16 + c;
                const bf16x8 b = *(const bf16x8*)&w1lds[j * 128 + 64 + ((s * 32 + g * 8) ^ ((j & 7) << 3))];
#pragma unroll
                for (int m = 0; m < 4; ++m)
                    cc[m][n] = __builtin_amdgcn_mfma_f32_16x16x32_bf16(af[m][s], b, cc[m][n], 0, 0, 0);
            }
#pragma unroll
        for (int n = 0; n < 4; ++n) {
            const float bb = be1[n * 16 + c];
#pragma unroll
            for (int m = 0; m < 4; ++m)
#pragma unroll
                for (int r = 0; r < 4; ++r) {
                    const int node = mbase + m * 16 + g * 4 + r;
                    if (node < NN) Pb[(size_t)node * 64 + n * 16 + c] = (__bf16)(cc[m][n][r] + bb);
                }
        }
    }
}

// ===========================================================================
__global__ __launch_bounds__(1024) void scan_kernel(const int* __restrict__ deg,
                                                    int* __restrict__ base)
{
    __shared__ int ts[1024];
    const int t = threadIdx.x;
    const int CH = (NN + 1023) / 1024;                // 49
    const int lo = t * CH;
    const int hi = (lo + CH < NN) ? (lo + CH) : NN;
    int s = 0;
    for (int i = lo; i < hi; ++i) s += deg[i];
    ts[t] = s;
    __syncthreads();
    for (int d = 1; d < 1024; d <<= 1) {
        const int v = (t >= d) ? ts[t - d] : 0;
        __syncthreads();
        ts[t] += v;
        __syncthreads();
    }
    int run = ts[t] - s;                              // exclusive prefix
    for (int i = lo; i < hi; ++i) { base[i] = run; run += deg[i]; }
}

// ===========================================================================
// scatter (atomic-free via precomputed ranks) + agg3 zeroing
__global__ __launch_bounds__(256) void scatter_kernel(
    const int* __restrict__ el, const int* __restrict__ base,
    const int* __restrict__ rank, int2* __restrict__ sorted_el,
    float* __restrict__ agg3)
{
    const int e = blockIdx.x * 256 + threadIdx.x;
    if (e < NN * 3) agg3[e] = 0.f;
    const int2 pr = ((const int2*)el)[e];
    sorted_el[base[pr.y] + rank[e]] = pr;
}

// ===========================================================================
// Edge kernel, sorted edges. 4 waves/block, 64 edges/wave, MFMA GEMMs,
// run-compressed segmented aggregation. (be1 pre-folded into Pb.)
__global__ __launch_bounds__(256) void edge_mfma(
    const __bf16* __restrict__ Pa, const __bf16* __restrict__ Pb,
    const float* __restrict__ coord, const int2* __restrict__ sorted_el,
    const float* __restrict__ We1,
    const __bf16* __restrict__ W2T, const float* __restrict__ be2,
    const __bf16* __restrict__ Wc1T, const float* __restrict__ bc1,
    const float* __restrict__ wc,
    float* __restrict__ agg_edge, float* __restrict__ agg3)
{
    __shared__ __align__(16) __bf16 tile[4][64 * 64];  // ef, XOR-swizzled
    __shared__ int   nin_s[4][64];
    __shared__ int   nout_s[4][64];
    __shared__ float rad_s[4][64];
    __shared__ float tw_s[4][64];
    __shared__ float cd_s[4][64][3];

    const int w    = threadIdx.x >> 6;
    const int lane = threadIdx.x & 63;
    const int c    = lane & 15;
    const int g    = lane >> 4;
    const int ebase = blockIdx.x * 256 + w * 64;       // NE = 3125*256 exact

    // ---- phase 1: lane = edge (sorted) ----
    const int2 pr = sorted_el[ebase + lane];
    const int nin = pr.x, nout = pr.y;
    nin_s[w][lane]  = nin;
    nout_s[w][lane] = nout;
    const float cdx = coord[3 * nout + 0] - coord[3 * nin + 0];
    const float cdy = coord[3 * nout + 1] - coord[3 * nin + 1];
    const float cdz = coord[3 * nout + 2] - coord[3 * nin + 2];
    rad_s[w][lane] = cdx * cdx + cdy * cdy + cdz * cdz;
    cd_s[w][lane][0] = cdx; cd_s[w][lane][1] = cdy; cd_s[w][lane][2] = cdz;

    // ---- build A fragments of h directly in MFMA A-layout ----
    bf16x8 af[4][2];
#pragma unroll
    for (int s = 0; s < 2; ++s) {
        const int k0 = s * 32 + g * 8;
        const float4 w1a = *(const float4*)(We1 + 128 * 64 + k0);
        const float4 w1b = *(const float4*)(We1 + 128 * 64 + k0 + 4);
        float wv[8] = {w1a.x, w1a.y, w1a.z, w1a.w, w1b.x, w1b.y, w1b.z, w1b.w};
#pragma unroll
        for (int m = 0; m < 4; ++m) {
            const int e  = m * 16 + c;
            const int ni = nin_s[w][e];
            const int no = nout_s[w][e];
            const float rad = rad_s[w][e];
            const bf16x8 pa = *(const bf16x8*)(Pa + (size_t)ni * 64 + k0);
            const bf16x8 pb = *(const bf16x8*)(Pb + (size_t)no * 64 + k0);
            bf16x8 a;
#pragma unroll
            for (int i = 0; i < 8; ++i)
                a[i] = (__bf16)frelu((float)pa[i] + (float)pb[i] + rad * wv[i]);
            af[m][s] = a;
        }
    }

    // ---- GEMM1: ef = relu(h @ We2 + be2) ----
    f32x4 c1[4][4];
#pragma unroll
    for (int n = 0; n < 4; ++n) {
        const float b = be2[n * 16 + c];
#pragma unroll
        for (int m = 0; m < 4; ++m) c1[m][n] = (f32x4){b, b, b, b};
    }
#pragma unroll
    for (int n = 0; n < 4; ++n)
#pragma unroll
        for (int s = 0; s < 2; ++s) {
            const bf16x8 b = *(const bf16x8*)(W2T + (n * 16 + c) * 64 + s * 32 + g * 8);
#pragma unroll
            for (int m = 0; m < 4; ++m)
                c1[m][n] = __builtin_amdgcn_mfma_f32_16x16x32_bf16(af[m][s], b, c1[m][n], 0, 0, 0);
        }

    // ---- relu -> stash ef (bf16, swizzled LDS) ----
#pragma unroll
    for (int m = 0; m < 4; ++m)
#pragma unroll
        for (int n = 0; n < 4; ++n)
#pragma unroll
            for (int r = 0; r < 4; ++r) {
                const int e = m * 16 + g * 4 + r;
                tile[w][e * 64 + ((n * 16 + c) ^ ((e & 7) << 3))] = (__bf16)frelu(c1[m][n][r]);
            }

    // ---- GEMM2: t = relu(ef @ Wc1 + bc1) ----
    bf16x8 a2[4][2];
#pragma unroll
    for (int m = 0; m < 4; ++m) {
        const int e = m * 16 + c;
#pragma unroll
        for (int s = 0; s < 2; ++s) {
            const int k0 = s * 32 + g * 8;
            a2[m][s] = *(const bf16x8*)&tile[w][e * 64 + (k0 ^ ((e & 7) << 3))];
        }
    }
    f32x4 c2[4][4];
#pragma unroll
    for (int n = 0; n < 4; ++n) {
        const float b = bc1[n * 16 + c];
#pragma unroll
        for (int m = 0; m < 4; ++m) c2[m][n] = (f32x4){b, b, b, b};
    }
#pragma unroll
    for (int n = 0; n < 4; ++n)
#pragma unroll
        for (int s = 0; s < 2; ++s) {
            const bf16x8 b = *(const bf16x8*)(Wc1T + (n * 16 + c) * 64 + s * 32 + g * 8);
#pragma unroll
            for (int m = 0; m < 4; ++m)
                c2[m][n] = __builtin_amdgcn_mfma_f32_16x16x32_bf16(a2[m][s], b, c2[m][n], 0, 0, 0);
        }

    // ---- tw = relu(c2) @ wc : 16-lane butterfly reduce ----
    float wcv[4];
#pragma unroll
    for (int n = 0; n < 4; ++n) wcv[n] = wc[n * 16 + c];
#pragma unroll
    for (int m = 0; m < 4; ++m) {
#pragma unroll
        for (int r = 0; r < 4; ++r) {
            float p = 0.f;
#pragma unroll
            for (int n = 0; n < 4; ++n) p = fmaf(frelu(c2[m][n][r]), wcv[n], p);
            p += __shfl_xor(p, 1);
            p += __shfl_xor(p, 2);
            p += __shfl_xor(p, 4);
            p += __shfl_xor(p, 8);
            if (c == 0) tw_s[w][m * 16 + g * 4 + r] = p;
        }
    }

    // ---- agg_edge: lane = feature column, run-compressed over sorted rows ----
    {
        int cur = nout_s[w][0];
        float acc = 0.f;
        for (int r = 0; r < 64; ++r) {
            acc += (float)tile[w][r * 64 + (lane ^ ((r & 7) << 3))];
            const int nxt = (r < 63) ? nout_s[w][r + 1] : -1;
            if (nxt != cur) {   // wave-uniform branch
                atomicAdd(&agg_edge[(size_t)cur * 64 + lane], acc);
                acc = 0.f;
                cur = nxt;
            }
        }
    }

    // ---- coord agg: 48 lanes = 16 row-chunks x 3 dims, run-compressed ----
    if (lane < 48) {
        const int dim = lane % 3, chunk = lane / 3;   // chunk 0..15
        const int r0 = chunk * 4;
        int cur = nout_s[w][r0];
        float acc = 0.f;
#pragma unroll
        for (int rr = 0; rr < 4; ++rr) {
            const int r = r0 + rr;
            acc += cd_s[w][r][dim] * tw_s[w][r];
            const int nxt = (rr < 3) ? nout_s[w][r + 1] : -1;
            if (nxt != cur) {
                atomicAdd(&agg3[3 * cur + dim], acc);
                acc = 0.f;
                cur = nxt;
            }
        }
    }
}

// ===========================================================================
// Node kernel: coord finalize + node MLP via MFMA. 4 waves/block.
__global__ __launch_bounds__(256) void node_mfma(
    const float* __restrict__ nf, const float* __restrict__ coord,
    const float* __restrict__ agg_edge, const int* __restrict__ deg,
    float* agg3_coordout,
    const __bf16* __restrict__ Wn1T, const float* __restrict__ bn1,
    const __bf16* __restrict__ Wn2T, const float* __restrict__ bn2,
    float* __restrict__ out_feat)
{
    __shared__ __align__(16) __bf16 tile[4][64 * 64];
    const int t = threadIdx.x;
    const int w = t >> 6, lane = t & 63, c = lane & 15, g = lane >> 4;
    const int nblk = blockIdx.x * 256;

    // coord_out = coord + agg3/max(cnt,1), in place (agg3 aliases out_coord)
    const int nodeT = nblk + t;
    if (nodeT < NN) {
        const float invc = 1.f / fmaxf((float)deg[nodeT], 1.f);
#pragma unroll
        for (int d = 0; d < 3; ++d) {
            const float a = agg3_coordout[3 * nodeT + d];
            agg3_coordout[3 * nodeT + d] = coord[3 * nodeT + d] + a * invc;
        }
    }

    const int mbase = nblk + w * 64;

    // A frags: [nf || agg_edge] rows, K=128 (s=0,1: nf; s=2,3: agg_edge)
    bf16x8 a1[4][4];
#pragma unroll
    for (int m = 0; m < 4; ++m) {
        int node = mbase + m * 16 + c;
        node = (node < NN) ? node : (NN - 1);
#pragma unroll
        for (int s = 0; s < 4; ++s) {
            const int k0 = s * 32 + g * 8;
            const float* src = (k0 < 64) ? (nf + (size_t)node * 64 + k0)
                                         : (agg_edge + (size_t)node * 64 + (k0 - 64));
            const float4 v0 = *(const float4*)src;
            const float4 v1 = *(const float4*)(src + 4);
            bf16x8 a;
            a[0] = (__bf16)v0.x; a[1] = (__bf16)v0.y; a[2] = (__bf16)v0.z; a[3] = (__bf16)v0.w;
            a[4] = (__bf16)v1.x; a[5] = (__bf16)v1.y; a[6] = (__bf16)v1.z; a[7] = (__bf16)v1.w;
            a1[m][s] = a;
        }
    }

    // GEMM1: h1 = relu([nf||agg] @ Wn1 + bn1)
    f32x4 c1[4][4];
#pragma unroll
    for (int n = 0; n < 4; ++n) {
        const float b = bn1[n * 16 + c];
#pragma unroll
        for (int m = 0; m < 4; ++m) c1[m][n] = (f32x4){b, b, b, b};
    }
#pragma unroll
    for (int n = 0; n < 4; ++n)
#pragma unroll
        for (int s = 0; s < 4; ++s) {
            const bf16x8 b = *(const bf16x8*)(Wn1T + (n * 16 + c) * 128 + s * 32 + g * 8);
#pragma unroll
            for (int m = 0; m < 4; ++m)
                c1[m][n] = __builtin_amdgcn_mfma_f32_16x16x32_bf16(a1[m][s], b, c1[m][n], 0, 0, 0);
        }

    // stash relu(h1) swizzled
#pragma unroll
    for (int m = 0; m < 4; ++m)
#pragma unroll
        for (int n = 0; n < 4; ++n)
#pragma unroll
            for (int r = 0; r < 4; ++r) {
                const int e = m * 16 + g * 4 + r;
                tile[w][e * 64 + ((n * 16 + c) ^ ((e & 7) << 3))] = (__bf16)frelu(c1[m][n][r]);
            }

    // GEMM2: nf_out = h1 @ Wn2 + bn2
    bf16x8 a2[4][2];
#pragma unroll
    for (int m = 0; m < 4; ++m) {
        const int e = m * 16 + c;
#pragma unroll
        for (int s = 0; s < 2; ++s) {
            const int k0 = s * 32 + g * 8;
            a2[m][s] = *(const bf16x8*)&tile[w][e * 64 + (k0 ^ ((e & 7) << 3))];
        }
    }
    f32x4 c2[4][4];
#pragma unroll
    for (int n = 0; n < 4; ++n) {
        const float b = bn2[n * 16 + c];
#pragma unroll
        for (int m = 0; m < 4; ++m) c2[m][n] = (f32x4){b, b, b, b};
    }
#pragma unroll
    for (int n = 0; n < 4; ++n)
#pragma unroll
        for (int s = 0; s < 2; ++s) {
            const bf16x8 b = *(const bf16x8*)(Wn2T + (n * 16 + c) * 64 + s * 32 + g * 8);
#pragma unroll
            for (int m = 0; m < 4; ++m)
                c2[m][n] = __builtin_amdgcn_mfma_f32_16x16x32_bf16(a2[m][s], b, c2[m][n], 0, 0, 0);
        }

    // store: out_feat = nf + c2
#pragma unroll
    for (int m = 0; m < 4; ++m)
#pragma unroll
        for (int n = 0; n < 4; ++n)
#pragma unroll
            for (int r = 0; r < 4; ++r) {
                const int node = mbase + m * 16 + g * 4 + r;
                if (node < NN) {
                    const int col = n * 16 + c;
                    out_feat[(size_t)node * 64 + col] =
                        nf[(size_t)node * 64 + col] + c2[m][n][r];
                }
            }
}

// ===========================================================================
extern "C" void kernel_launch(void* const* d_in, const int* in_sizes, int n_in,
                              void* d_out, int out_size, void* d_ws, size_t ws_size,
                              hipStream_t stream)
{
    const float* nf    = (const float*)d_in[0];
    const float* coord = (const float*)d_in[1];
    const int*   el    = (const int*)d_in[2];
    const float* We1   = (const float*)d_in[3];
    const float* be1   = (const float*)d_in[4];
    const float* We2   = (const float*)d_in[5];
    const float* be2   = (const float*)d_in[6];
    const float* Wn1   = (const float*)d_in[7];
    const float* bn1   = (const float*)d_in[8];
    const float* Wn2   = (const float*)d_in[9];
    const float* bn2   = (const float*)d_in[10];
    const float* Wc1   = (const float*)d_in[11];
    const float* bc1   = (const float*)d_in[12];
    const float* wc    = (const float*)d_in[13];

    float* out_feat  = (float*)d_out;               // N*64 f32
    float* out_coord = out_feat + (size_t)NN * 64;  // N*3 f32

    // d_out borrows: Pa (bf16, first 6.4MB of out_feat), rank (next 3.2MB),
    // agg3 (= out_coord).  All dead by the time node_mfma writes out_feat.
    __bf16* Pa   = (__bf16*)d_out;
    int*    rank = (int*)((char*)d_out + 6400000);
    float*  agg3 = out_coord;

    // ws layout (bytes):
    char* ws = (char*)d_ws;
    __bf16* Pb       = (__bf16*)ws;                    //  6,400,000
    float* agg_edge  = (float*)(ws + 6400000);         // 12,800,000
    int*   deg       = (int*)(ws + 19200000);          //    200,000
    int*   base      = (int*)(ws + 19400000);          //    200,000
    int2*  sorted_el = (int2*)(ws + 19600000);         //  6,400,000
    __bf16* W2T  = (__bf16*)(ws + 26000000);           // 8192 B each
    __bf16* Wc1T = W2T + 4096;
    __bf16* Wn2T = Wc1T + 4096;
    __bf16* Wn1T = Wn2T + 4096;                        // 16384 B
    // total ws usage ~26.04 MB

    hipMemsetAsync(deg, 0, (size_t)NN * sizeof(int), stream);

    prep_kernel<<<dim3(PREP_BLOCKS), dim3(256), 0, stream>>>(
        nf, el, We1, We2, Wc1, Wn1, Wn2, be1,
        W2T, Wc1T, Wn1T, Wn2T,
        Pa, Pb, deg, rank, agg_edge);

    scan_kernel<<<dim3(1), dim3(1024), 0, stream>>>(deg, base);

    scatter_kernel<<<dim3(NE / 256), dim3(256), 0, stream>>>(
        el, base, rank, sorted_el, agg3);

    edge_mfma<<<dim3(NE / 256), dim3(256), 0, stream>>>(
        Pa, Pb, coord, sorted_el, We1, W2T, be2, Wc1T, bc1, wc,
        agg_edge, agg3);

    node_mfma<<<dim3((NN + 255) / 256), dim3(256), 0, stream>>>(
        nf, coord, agg_edge, deg, agg3, Wn1T, bn1, Wn2T, bn2, out_feat);
}

// Round 6
// 194.978 us; speedup vs baseline: 15.9906x; 1.4478x over previous
//
#include <hip/hip_runtime.h>

#define NN 50000
#define NE 800000
#define PREP_BLOCKS 784
#define PREP_THREADS (PREP_BLOCKS * 256)

typedef __bf16 bf16x8 __attribute__((ext_vector_type(8)));
typedef float  f32x4  __attribute__((ext_vector_type(4)));

__device__ __forceinline__ float frelu(float x) { return fmaxf(x, 0.f); }

// ===========================================================================
// prep: weight prep for later kernels + agg_edge zero + histogram with ranks
//       + Pa/Pb precompute (We1 via block-local LDS transpose). counter=0.
__global__ __launch_bounds__(256) void prep_kernel(
    const float* __restrict__ nf, const int* __restrict__ el,
    const float* __restrict__ We1, const float* __restrict__ We2,
    const float* __restrict__ Wc1, const float* __restrict__ Wn1,
    const float* __restrict__ Wn2, const float* __restrict__ be1,
    __bf16* __restrict__ W2T,  __bf16* __restrict__ Wc1T,
    __bf16* __restrict__ Wn1T, __bf16* __restrict__ Wn2T,
    __bf16* __restrict__ Pa, __bf16* __restrict__ Pb,
    int* __restrict__ deg, int* __restrict__ rank, float* __restrict__ agg_edge,
    int* __restrict__ counter)
{
    __shared__ __align__(16) __bf16 w1lds[64 * 128];
    if (blockIdx.x < 196) {
        for (int idx = threadIdx.x; idx < 64 * 128; idx += 256) {
            const int k = idx >> 6;          // 0..127
            const int j = idx & 63;
            w1lds[j * 128 + (k ^ ((j & 7) << 3))] = (__bf16)We1[k * 64 + j];
        }
    }

    const int tid = blockIdx.x * 256 + threadIdx.x;
    if (tid == 0) *counter = 0;

    // ---- weight transpose for later kernels (first 4096 threads) ----
    if (tid < 4096) {
        const int j = tid & 63, k = tid >> 6;
        W2T [j * 64 + k] = (__bf16)We2[k * 64 + j];
        Wc1T[j * 64 + k] = (__bf16)Wc1[k * 64 + j];
        Wn2T[j * 64 + k] = (__bf16)Wn2[k * 64 + j];
        Wn1T[j * 128 + k]      = (__bf16)Wn1[k * 64 + j];
        Wn1T[j * 128 + 64 + k] = (__bf16)Wn1[(64 + k) * 64 + j];
    }

    // ---- agg_edge zero (3.2M floats as float4) ----
    {
        const f32x4 z = (f32x4){0.f, 0.f, 0.f, 0.f};
        for (int i = tid; i < NN * 16; i += PREP_THREADS)
            ((f32x4*)agg_edge)[i] = z;
    }

    // ---- histogram + rank (deg memset to 0 before this kernel) ----
    for (int e = tid; e < NE; e += PREP_THREADS) {
        const int2 pr = ((const int2*)el)[e];
        rank[e] = atomicAdd(&deg[pr.y], 1);
    }

    if (blockIdx.x >= 196) return;
    __syncthreads();   // w1lds ready

    // ---- Pa/Pb MFMA precompute ----
    const int w = threadIdx.x >> 6, lane = threadIdx.x & 63;
    const int c = lane & 15, g = lane >> 4;
    const int mbase = blockIdx.x * 256 + w * 64;

    bf16x8 af[4][2];
#pragma unroll
    for (int m = 0; m < 4; ++m) {
        int node = mbase + m * 16 + c;
        node = (node < NN) ? node : (NN - 1);
#pragma unroll
        for (int s = 0; s < 2; ++s) {
            const int k0 = s * 32 + g * 8;
            const float4 v0 = *(const float4*)(nf + (size_t)node * 64 + k0);
            const float4 v1 = *(const float4*)(nf + (size_t)node * 64 + k0 + 4);
            bf16x8 a;
            a[0] = (__bf16)v0.x; a[1] = (__bf16)v0.y; a[2] = (__bf16)v0.z; a[3] = (__bf16)v0.w;
            a[4] = (__bf16)v1.x; a[5] = (__bf16)v1.y; a[6] = (__bf16)v1.z; a[7] = (__bf16)v1.w;
            af[m][s] = a;
        }
    }

    // Pa = nf @ We1[0:64,:]
    {
        f32x4 cc[4][4];
#pragma unroll
        for (int m = 0; m < 4; ++m)
#pragma unroll
            for (int n = 0; n < 4; ++n) cc[m][n] = (f32x4){0.f, 0.f, 0.f, 0.f};
#pragma unroll
        for (int n = 0; n < 4; ++n)
#pragma unroll
            for (int s = 0; s < 2; ++s) {
                const int j = n * 16 + c;
                const bf16x8 b = *(const bf16x8*)&w1lds[j * 128 + ((s * 32 + g * 8) ^ ((j & 7) << 3))];
#pragma unroll
                for (int m = 0; m < 4; ++m)
                    cc[m][n] = __builtin_amdgcn_mfma_f32_16x16x32_bf16(af[m][s], b, cc[m][n], 0, 0, 0);
            }
#pragma unroll
        for (int m = 0; m < 4; ++m)
#pragma unroll
            for (int n = 0; n < 4; ++n)
#pragma unroll
                for (int r = 0; r < 4; ++r) {
                    const int node = mbase + m * 16 + g * 4 + r;
                    if (node < NN) Pa[(size_t)node * 64 + n * 16 + c] = (__bf16)cc[m][n][r];
                }
    }
    // Pb = nf @ We1[64:128,:] + be1 (folded)
    {
        f32x4 cc[4][4];
#pragma unroll
        for (int m = 0; m < 4; ++m)
#pragma unroll
            for (int n = 0; n < 4; ++n) cc[m][n] = (f32x4){0.f, 0.f, 0.f, 0.f};
#pragma unroll
        for (int n = 0; n < 4; ++n)
#pragma unroll
            for (int s = 0; s < 2; ++s) {
                const int j = n * 16 + c;
                const bf16x8 b = *(const bf16x8*)&w1lds[j * 128 + 64 + ((s * 32 + g * 8) ^ ((j & 7) << 3))];
#pragma unroll
                for (int m = 0; m < 4; ++m)
                    cc[m][n] = __builtin_amdgcn_mfma_f32_16x16x32_bf16(af[m][s], b, cc[m][n], 0, 0, 0);
            }
#pragma unroll
        for (int n = 0; n < 4; ++n) {
            const float bb = be1[n * 16 + c];
#pragma unroll
            for (int m = 0; m < 4; ++m)
#pragma unroll
                for (int r = 0; r < 4; ++r) {
                    const int node = mbase + m * 16 + g * 4 + r;
                    if (node < NN) Pb[(size_t)node * 64 + n * 16 + c] = (__bf16)(cc[m][n][r] + bb);
                }
        }
    }
}

// ===========================================================================
// Group-base allocation: base[n] = bump-allocated range of size deg[n].
// Group ORDER is arbitrary (counting sort only needs grouping, not order).
__global__ __launch_bounds__(256) void alloc_kernel(
    const int* __restrict__ deg, int* __restrict__ base, int* __restrict__ counter)
{
    const int n = blockIdx.x * 256 + threadIdx.x;
    const int lid = threadIdx.x & 63;
    const int d = (n < NN) ? deg[n] : 0;
    int pre = d;
#pragma unroll
    for (int off = 1; off < 64; off <<= 1) {
        const int v = __shfl_up(pre, off);
        if (lid >= off) pre += v;
    }
    const int excl = pre - d;
    const int tot = __shfl(pre, 63);
    int wbase = 0;
    if (lid == 63) wbase = atomicAdd(counter, tot);
    wbase = __shfl(wbase, 63);
    if (n < NN) base[n] = wbase + excl;
}

// ===========================================================================
// scatter (atomic-free via precomputed ranks) + agg3 zeroing
__global__ __launch_bounds__(256) void scatter_kernel(
    const int* __restrict__ el, const int* __restrict__ base,
    const int* __restrict__ rank, int2* __restrict__ sorted_el,
    float* __restrict__ agg3)
{
    const int e = blockIdx.x * 256 + threadIdx.x;
    if (e < NN * 3) agg3[e] = 0.f;
    const int2 pr = ((const int2*)el)[e];
    sorted_el[base[pr.y] + rank[e]] = pr;
}

// ===========================================================================
// Edge kernel, grouped edges. 4 waves/block, 64 edges/wave, MFMA GEMMs,
// run-compressed segmented aggregation. Half-width ef tile (two col phases)
// cuts LDS to 23.5KB/block for higher occupancy.
__global__ __launch_bounds__(256, 5) void edge_mfma(
    const __bf16* __restrict__ Pa, const __bf16* __restrict__ Pb,
    const float* __restrict__ coord, const int2* __restrict__ sorted_el,
    const float* __restrict__ We1,
    const __bf16* __restrict__ W2T, const float* __restrict__ be2,
    const __bf16* __restrict__ Wc1T, const float* __restrict__ bc1,
    const float* __restrict__ wc,
    float* __restrict__ agg_edge, float* __restrict__ agg3)
{
    __shared__ __align__(16) __bf16 tile[4][64 * 32];  // half-width ef, swizzled
    __shared__ int   nin_s[4][64];
    __shared__ int   nout_s[4][64];
    __shared__ float rad_s[4][64];
    __shared__ float tw_s[4][64];
    __shared__ float cd_s[4][64][3];

    const int w    = threadIdx.x >> 6;
    const int lane = threadIdx.x & 63;
    const int c    = lane & 15;
    const int g    = lane >> 4;
    const int ebase = blockIdx.x * 256 + w * 64;       // NE = 3125*256 exact

    // ---- phase 1: lane = edge (grouped by nout) ----
    const int2 pr = sorted_el[ebase + lane];
    const int nin = pr.x, nout = pr.y;
    nin_s[w][lane]  = nin;
    nout_s[w][lane] = nout;
    const float cdx = coord[3 * nout + 0] - coord[3 * nin + 0];
    const float cdy = coord[3 * nout + 1] - coord[3 * nin + 1];
    const float cdz = coord[3 * nout + 2] - coord[3 * nin + 2];
    rad_s[w][lane] = cdx * cdx + cdy * cdy + cdz * cdz;
    cd_s[w][lane][0] = cdx; cd_s[w][lane][1] = cdy; cd_s[w][lane][2] = cdz;

    // ---- build A fragments of h directly in MFMA A-layout ----
    bf16x8 af[4][2];
#pragma unroll
    for (int s = 0; s < 2; ++s) {
        const int k0 = s * 32 + g * 8;
        const float4 w1a = *(const float4*)(We1 + 128 * 64 + k0);
        const float4 w1b = *(const float4*)(We1 + 128 * 64 + k0 + 4);
        float wv[8] = {w1a.x, w1a.y, w1a.z, w1a.w, w1b.x, w1b.y, w1b.z, w1b.w};
#pragma unroll
        for (int m = 0; m < 4; ++m) {
            const int e  = m * 16 + c;
            const int ni = nin_s[w][e];
            const int no = nout_s[w][e];
            const float rad = rad_s[w][e];
            const bf16x8 pa = *(const bf16x8*)(Pa + (size_t)ni * 64 + k0);
            const bf16x8 pb = *(const bf16x8*)(Pb + (size_t)no * 64 + k0);
            bf16x8 a;
#pragma unroll
            for (int i = 0; i < 8; ++i)
                a[i] = (__bf16)frelu((float)pa[i] + (float)pb[i] + rad * wv[i]);
            af[m][s] = a;
        }
    }

    // ---- GEMM1 + ef staging + agg, in two 32-column phases ----
    bf16x8 a2[4][2];
#pragma unroll
    for (int p = 0; p < 2; ++p) {
        // GEMM1 for output cols n = 2p, 2p+1
        f32x4 c1h[4][2];
#pragma unroll
        for (int q = 0; q < 2; ++q) {
            const float b = be2[(2 * p + q) * 16 + c];
#pragma unroll
            for (int m = 0; m < 4; ++m) c1h[m][q] = (f32x4){b, b, b, b};
        }
#pragma unroll
        for (int q = 0; q < 2; ++q)
#pragma unroll
            for (int s = 0; s < 2; ++s) {
                const bf16x8 b = *(const bf16x8*)(W2T + ((2 * p + q) * 16 + c) * 64 + s * 32 + g * 8);
#pragma unroll
                for (int m = 0; m < 4; ++m)
                    c1h[m][q] = __builtin_amdgcn_mfma_f32_16x16x32_bf16(af[m][s], b, c1h[m][q], 0, 0, 0);
            }

        // stash relu(ef) half-tile (local col = q*16+c), swizzled
#pragma unroll
        for (int m = 0; m < 4; ++m)
#pragma unroll
            for (int q = 0; q < 2; ++q)
#pragma unroll
                for (int r = 0; r < 4; ++r) {
                    const int e = m * 16 + g * 4 + r;
                    const int lc = q * 16 + c;
                    tile[w][e * 32 + (lc ^ (((e >> 1) & 3) << 3))] = (__bf16)frelu(c1h[m][q][r]);
                }

        // read GEMM2 A-frags for k-range p*32..p*32+31
#pragma unroll
        for (int m = 0; m < 4; ++m) {
            const int e = m * 16 + c;
            a2[m][p] = *(const bf16x8*)&tile[w][e * 32 + ((g * 8) ^ (((e >> 1) & 3) << 3))];
        }

        // agg_edge for cols p*32..p*32+31: 2 lanes/col, rows split 0-31/32-63
        {
            const int lc = lane & 31;
            const int rbase = (lane >> 5) * 32;
            int cur = nout_s[w][rbase];
            float acc = 0.f;
#pragma unroll 4
            for (int rr = 0; rr < 32; ++rr) {
                const int r = rbase + rr;
                acc += (float)tile[w][r * 32 + (lc ^ (((r >> 1) & 3) << 3))];
                const int nxt = (rr < 31) ? nout_s[w][r + 1] : -1;
                if (nxt != cur) {
                    atomicAdd(&agg_edge[(size_t)cur * 64 + p * 32 + lc], acc);
                    acc = 0.f;
                    cur = nxt;
                }
            }
        }
    }

    // ---- GEMM2 (t = relu(ef @ Wc1 + bc1)) folded into tw per n ----
    f32x4 twp[4];
#pragma unroll
    for (int m = 0; m < 4; ++m) twp[m] = (f32x4){0.f, 0.f, 0.f, 0.f};
#pragma unroll
    for (int n = 0; n < 4; ++n) {
        const float b = bc1[n * 16 + c];
        const float wn = wc[n * 16 + c];
        f32x4 c2[4];
#pragma unroll
        for (int m = 0; m < 4; ++m) c2[m] = (f32x4){b, b, b, b};
#pragma unroll
        for (int s = 0; s < 2; ++s) {
            const bf16x8 bb = *(const bf16x8*)(Wc1T + (n * 16 + c) * 64 + s * 32 + g * 8);
#pragma unroll
            for (int m = 0; m < 4; ++m)
                c2[m] = __builtin_amdgcn_mfma_f32_16x16x32_bf16(a2[m][s], bb, c2[m], 0, 0, 0);
        }
#pragma unroll
        for (int m = 0; m < 4; ++m)
#pragma unroll
            for (int r = 0; r < 4; ++r)
                twp[m][r] = fmaf(frelu(c2[m][r]), wn, twp[m][r]);
    }

    // ---- tw: 16-lane butterfly reduce ----
#pragma unroll
    for (int m = 0; m < 4; ++m) {
#pragma unroll
        for (int r = 0; r < 4; ++r) {
            float p = twp[m][r];
            p += __shfl_xor(p, 1);
            p += __shfl_xor(p, 2);
            p += __shfl_xor(p, 4);
            p += __shfl_xor(p, 8);
            if (c == 0) tw_s[w][m * 16 + g * 4 + r] = p;
        }
    }

    // ---- coord agg: 48 lanes = 16 row-chunks x 3 dims, run-compressed ----
    if (lane < 48) {
        const int dim = lane % 3, chunk = lane / 3;   // chunk 0..15
        const int r0 = chunk * 4;
        int cur = nout_s[w][r0];
        float acc = 0.f;
#pragma unroll
        for (int rr = 0; rr < 4; ++rr) {
            const int r = r0 + rr;
            acc += cd_s[w][r][dim] * tw_s[w][r];
            const int nxt = (rr < 3) ? nout_s[w][r + 1] : -1;
            if (nxt != cur) {
                atomicAdd(&agg3[3 * cur + dim], acc);
                acc = 0.f;
                cur = nxt;
            }
        }
    }
}

// ===========================================================================
// Node kernel: coord finalize + node MLP via MFMA. 4 waves/block.
__global__ __launch_bounds__(256) void node_mfma(
    const float* __restrict__ nf, const float* __restrict__ coord,
    const float* __restrict__ agg_edge, const int* __restrict__ deg,
    float* agg3_coordout,
    const __bf16* __restrict__ Wn1T, const float* __restrict__ bn1,
    const __bf16* __restrict__ Wn2T, const float* __restrict__ bn2,
    float* __restrict__ out_feat)
{
    __shared__ __align__(16) __bf16 tile[4][64 * 64];
    const int t = threadIdx.x;
    const int w = t >> 6, lane = t & 63, c = lane & 15, g = lane >> 4;
    const int nblk = blockIdx.x * 256;

    const int nodeT = nblk + t;
    if (nodeT < NN) {
        const float invc = 1.f / fmaxf((float)deg[nodeT], 1.f);
#pragma unroll
        for (int d = 0; d < 3; ++d) {
            const float a = agg3_coordout[3 * nodeT + d];
            agg3_coordout[3 * nodeT + d] = coord[3 * nodeT + d] + a * invc;
        }
    }

    const int mbase = nblk + w * 64;

    bf16x8 a1[4][4];
#pragma unroll
    for (int m = 0; m < 4; ++m) {
        int node = mbase + m * 16 + c;
        node = (node < NN) ? node : (NN - 1);
#pragma unroll
        for (int s = 0; s < 4; ++s) {
            const int k0 = s * 32 + g * 8;
            const float* src = (k0 < 64) ? (nf + (size_t)node * 64 + k0)
                                         : (agg_edge + (size_t)node * 64 + (k0 - 64));
            const float4 v0 = *(const float4*)src;
            const float4 v1 = *(const float4*)(src + 4);
            bf16x8 a;
            a[0] = (__bf16)v0.x; a[1] = (__bf16)v0.y; a[2] = (__bf16)v0.z; a[3] = (__bf16)v0.w;
            a[4] = (__bf16)v1.x; a[5] = (__bf16)v1.y; a[6] = (__bf16)v1.z; a[7] = (__bf16)v1.w;
            a1[m][s] = a;
        }
    }

    f32x4 c1[4][4];
#pragma unroll
    for (int n = 0; n < 4; ++n) {
        const float b = bn1[n * 16 + c];
#pragma unroll
        for (int m = 0; m < 4; ++m) c1[m][n] = (f32x4){b, b, b, b};
    }
#pragma unroll
    for (int n = 0; n < 4; ++n)
#pragma unroll
        for (int s = 0; s < 4; ++s) {
            const bf16x8 b = *(const bf16x8*)(Wn1T + (n * 16 + c) * 128 + s * 32 + g * 8);
#pragma unroll
            for (int m = 0; m < 4; ++m)
                c1[m][n] = __builtin_amdgcn_mfma_f32_16x16x32_bf16(a1[m][s], b, c1[m][n], 0, 0, 0);
        }

#pragma unroll
    for (int m = 0; m < 4; ++m)
#pragma unroll
        for (int n = 0; n < 4; ++n)
#pragma unroll
            for (int r = 0; r < 4; ++r) {
                const int e = m * 16 + g * 4 + r;
                tile[w][e * 64 + ((n * 16 + c) ^ ((e & 7) << 3))] = (__bf16)frelu(c1[m][n][r]);
            }

    bf16x8 a2[4][2];
#pragma unroll
    for (int m = 0; m < 4; ++m) {
        const int e = m * 16 + c;
#pragma unroll
        for (int s = 0; s < 2; ++s) {
            const int k0 = s * 32 + g * 8;
            a2[m][s] = *(const bf16x8*)&tile[w][e * 64 + (k0 ^ ((e & 7) << 3))];
        }
    }
    f32x4 c2[4][4];
#pragma unroll
    for (int n = 0; n < 4; ++n) {
        const float b = bn2[n * 16 + c];
#pragma unroll
        for (int m = 0; m < 4; ++m) c2[m][n] = (f32x4){b, b, b, b};
    }
#pragma unroll
    for (int n = 0; n < 4; ++n)
#pragma unroll
        for (int s = 0; s < 2; ++s) {
            const bf16x8 b = *(const bf16x8*)(Wn2T + (n * 16 + c) * 64 + s * 32 + g * 8);
#pragma unroll
            for (int m = 0; m < 4; ++m)
                c2[m][n] = __builtin_amdgcn_mfma_f32_16x16x32_bf16(a2[m][s], b, c2[m][n], 0, 0, 0);
        }

#pragma unroll
    for (int m = 0; m < 4; ++m)
#pragma unroll
        for (int n = 0; n < 4; ++n)
#pragma unroll
            for (int r = 0; r < 4; ++r) {
                const int node = mbase + m * 16 + g * 4 + r;
                if (node < NN) {
                    const int col = n * 16 + c;
                    out_feat[(size_t)node * 64 + col] =
                        nf[(size_t)node * 64 + col] + c2[m][n][r];
                }
            }
}

// ===========================================================================
extern "C" void kernel_launch(void* const* d_in, const int* in_sizes, int n_in,
                              void* d_out, int out_size, void* d_ws, size_t ws_size,
                              hipStream_t stream)
{
    const float* nf    = (const float*)d_in[0];
    const float* coord = (const float*)d_in[1];
    const int*   el    = (const int*)d_in[2];
    const float* We1   = (const float*)d_in[3];
    const float* be1   = (const float*)d_in[4];
    const float* We2   = (const float*)d_in[5];
    const float* be2   = (const float*)d_in[6];
    const float* Wn1   = (const float*)d_in[7];
    const float* bn1   = (const float*)d_in[8];
    const float* Wn2   = (const float*)d_in[9];
    const float* bn2   = (const float*)d_in[10];
    const float* Wc1   = (const float*)d_in[11];
    const float* bc1   = (const float*)d_in[12];
    const float* wc    = (const float*)d_in[13];

    float* out_feat  = (float*)d_out;               // N*64 f32
    float* out_coord = out_feat + (size_t)NN * 64;  // N*3 f32

    __bf16* Pa   = (__bf16*)d_out;                  // 6.4MB of out_feat region
    int*    rank = (int*)((char*)d_out + 6400000);  // 3.2MB
    float*  agg3 = out_coord;

    char* ws = (char*)d_ws;
    __bf16* Pb       = (__bf16*)ws;                    //  6,400,000
    float* agg_edge  = (float*)(ws + 6400000);         // 12,800,000
    int*   deg       = (int*)(ws + 19200000);          //    200,000
    int*   base      = (int*)(ws + 19400000);          //    200,000
    int2*  sorted_el = (int2*)(ws + 19600000);         //  6,400,000
    __bf16* W2T  = (__bf16*)(ws + 26000000);           // 8192 B each
    __bf16* Wc1T = W2T + 4096;
    __bf16* Wn2T = Wc1T + 4096;
    __bf16* Wn1T = Wn2T + 4096;                        // 16384 B
    int*   counter = (int*)(ws + 26041000);            // 4 B (zeroed in prep)

    hipMemsetAsync(deg, 0, (size_t)NN * sizeof(int), stream);

    prep_kernel<<<dim3(PREP_BLOCKS), dim3(256), 0, stream>>>(
        nf, el, We1, We2, Wc1, Wn1, Wn2, be1,
        W2T, Wc1T, Wn1T, Wn2T,
        Pa, Pb, deg, rank, agg_edge, counter);

    alloc_kernel<<<dim3((NN + 255) / 256), dim3(256), 0, stream>>>(deg, base, counter);

    scatter_kernel<<<dim3(NE / 256), dim3(256), 0, stream>>>(
        el, base, rank, sorted_el, agg3);

    edge_mfma<<<dim3(NE / 256), dim3(256), 0, stream>>>(
        Pa, Pb, coord, sorted_el, We1, W2T, be2, Wc1T, bc1, wc,
        agg_edge, agg3);

    node_mfma<<<dim3((NN + 255) / 256), dim3(256), 0, stream>>>(
        nf, coord, agg_edge, deg, agg3, Wn1T, bn1, Wn2T, bn2, out_feat);
}